// Round 4
// baseline (346.036 us; speedup 1.0000x reference)
//
#include <hip/hip_runtime.h>

#define SQ   2048
#define DIMD 2048
#define NH   16
#define HD   128
#define MR   4096   // B*S
#define QBLK 128
#define KBLK 64

using u16 = unsigned short;
using u32 = unsigned int;
using s16x8 = __attribute__((ext_vector_type(8))) short;
using u16x8 = __attribute__((ext_vector_type(8))) unsigned short;
using f32x4 = __attribute__((ext_vector_type(4))) float;
using as3u  = __attribute__((address_space(3))) u32;
using as1u  = __attribute__((address_space(1))) u32;

__device__ __forceinline__ u16 f2bf(float f) {
  u32 x = __float_as_uint(f);
  return (u16)((x + 0x7fffu + ((x >> 16) & 1u)) >> 16);
}
__device__ __forceinline__ float bf2f(u16 u) {
  return __uint_as_float(((u32)u) << 16);
}
__device__ __forceinline__ void gld16(const void* g, void* l) {
  __builtin_amdgcn_global_load_lds((as1u*)g, (as3u*)l, 16, 0, 0);
}
#define MFMA16 __builtin_amdgcn_mfma_f32_16x16x32_bf16

// ---------------- fp32 -> bf16 convert ----------------
__global__ __launch_bounds__(256) void cvt_bf16(const float* __restrict__ s,
                                                u16* __restrict__ d, int n4) {
  int i = blockIdx.x * 256 + threadIdx.x;
  int st = gridDim.x * 256;
  for (; i < n4; i += st) {
    float4 v = ((const float4*)s)[i];
    u32 lo = (u32)f2bf(v.x) | ((u32)f2bf(v.y) << 16);
    u32 hi = (u32)f2bf(v.z) | ((u32)f2bf(v.w) << 16);
    ((uint2*)d)[i] = make_uint2(lo, hi);
  }
}

// ---------------- RoPE (1 wave = 1 row of 128) ----------------
__global__ __launch_bounds__(256) void rope_kernel(
    const u16* __restrict__ Qin, const u16* __restrict__ Kin,
    u16* __restrict__ Qout, u16* __restrict__ Kout,
    const float* __restrict__ cosT, const float* __restrict__ sinT) {
  int ten = blockIdx.y;
  const u16* in = ten ? Kin : Qin;
  u16* outp     = ten ? Kout : Qout;
  float scl     = ten ? 1.0f : 0.08838834764831845f;  // fold 1/sqrt(DH) into Q
  int row = blockIdx.x * 4 + (threadIdx.x >> 6);
  int j   = threadIdx.x & 63;
  int s   = row & (SQ - 1);
  const u16* r = in + (size_t)row * HD;
  u16* w = outp + (size_t)row * HD;
  float c  = cosT[s * HD + j];
  float si = sinT[s * HD + j];
  float a  = bf2f(r[j]);
  float b  = bf2f(r[j + 64]);
  float ev = bf2f(r[2 * j]);
  float od = bf2f(r[2 * j + 1]);
  w[j]      = f2bf((a * c - od * si) * scl);
  w[j + 64] = f2bf((b * c + ev * si) * scl);
}

// ---------------- V (b,h,s,dh) -> Vt (b,h,dh,s) ----------------
__global__ __launch_bounds__(256) void transpose_v(const u16* __restrict__ V,
                                                   u16* __restrict__ Vt) {
  __shared__ u16 tile[64][72];
  int sb = blockIdx.x, db = blockIdx.y, bh = blockIdx.z;
  int r  = threadIdx.x >> 3;
  int c8 = (threadIdx.x & 7) * 8;
  const u16* src = V + ((size_t)bh * SQ + sb * 64) * HD + db * 64;
#pragma unroll
  for (int p2 = 0; p2 < 2; p2++) {
    int row = p2 * 32 + r;
    u16x8 v = *(const u16x8*)(src + (size_t)row * HD + c8);
#pragma unroll
    for (int k2 = 0; k2 < 8; k2++) tile[row][c8 + k2] = v[k2];
  }
  __syncthreads();
  u16* dst = Vt + ((size_t)bh * HD + db * 64) * SQ + sb * 64;
#pragma unroll
  for (int p2 = 0; p2 < 2; p2++) {
    int dr = p2 * 32 + r;
    u16x8 o;
#pragma unroll
    for (int k2 = 0; k2 < 8; k2++) o[k2] = tile[c8 + k2][dr];
    *(u16x8*)(dst + (size_t)dr * SQ + c8) = o;
  }
}

// ---------------- 8-phase GEMM  C = A(M,K) * W(N,K)^T -----------------------
// Tile 128x256, BK=64 in 2 k-halves of 32 (contiguous 8/16 KB staging units).
// 512 thr = 8 waves (2M x 4N), wave tile 64x64, acc[4][4].
// 4 phases per K-tile: (ks, mhalf). Counted vmcnt(3) twice per K-tile; stage
// order {Bk0,Ak0,Bk1,Ak1} of kt+1 so vmcnt(3) completes exactly the k-half
// needed two phases later. k-half rows are 64B -> frag reads spread 8
// lanes/bank = b128 floor, no swizzle needed.
// MODE 0: QKV (N=6144, W=[wq;wk;wv]) -> bf16 scatter to (b,h,s,dh), 3 tensors
// MODE 1: O-proj (N=2048) -> fp32 row-major
template <int MODE>
__global__ __launch_bounds__(512, 2) void gemm8p(
    const u16* __restrict__ A, const u16* __restrict__ W,
    u16* __restrict__ Obf, float* __restrict__ Ofp) {
  __shared__ alignas(16) u16 lA[2][2][128 * 32];  // [buf][kh] 8 KB each
  __shared__ alignas(16) u16 lB[2][2][256 * 32];  // [buf][kh] 16 KB each
  int t = threadIdx.x;
  int l = t & 63, l15 = l & 15, lg = l >> 4;
  int wid = t >> 6, wm = wid >> 2, wn = wid & 3;
  // bijective XCD swizzle; XCD gets contiguous li-range sharing W-panels
  int orig = blockIdx.x;
  int NBX = (MODE == 0) ? 96 : 32;   // blocks per XCD (768/8, 256/8)
  int li = (orig & 7) * NBX + (orig >> 3);
  int mB = li & 31, nB = li >> 5;
  int m0 = mB * 128, n0 = nB * 256;
  const u16* Ag = A + (size_t)m0 * DIMD;
  const u16* Wg = W + (size_t)n0 * DIMD;

  f32x4 acc[4][4];
#pragma unroll
  for (int a1 = 0; a1 < 4; a1++)
#pragma unroll
    for (int b1 = 0; b1 < 4; b1++) acc[a1][b1] = (f32x4){0.f, 0.f, 0.f, 0.f};

  // staging offsets: thread t covers bytes t*16 (and +8192 for B)
  int bo0 = t * 16, bo1 = t * 16 + 8192;
  int br0 = bo0 >> 6, bc0 = (bo0 & 63) >> 1;   // row, elem-col in k-half
  int br1 = bo1 >> 6, bc1 = (bo1 & 63) >> 1;

  auto stageB = [&](int buf, int kt, int kh) {
    const u16* src = Wg + kt * 64 + kh * 32;
    gld16(src + (size_t)br0 * DIMD + bc0, &lB[buf][kh][bo0 >> 1]);
    gld16(src + (size_t)br1 * DIMD + bc1, &lB[buf][kh][bo1 >> 1]);
  };
  auto stageA = [&](int buf, int kt, int kh) {
    const u16* src = Ag + kt * 64 + kh * 32;
    gld16(src + (size_t)br0 * DIMD + bc0, &lA[buf][kh][bo0 >> 1]);
  };
  auto rdA = [&](int buf, int kh, int mf) {
    return *(const s16x8*)&lA[buf][kh][(wm * 64 + mf * 16 + l15) * 32 + lg * 8];
  };
  auto rdB = [&](int buf, int kh, int nf) {
    return *(const s16x8*)&lB[buf][kh][(wn * 64 + nf * 16 + l15) * 32 + lg * 8];
  };

  const int NKT = DIMD / 64;  // 32 K-tiles
  // prologue: stage tile 0 fully; wait k-half0 only (3 loads stay in flight)
  stageB(0, 0, 0);
  stageA(0, 0, 0);
  stageB(0, 0, 1);
  stageA(0, 0, 1);
  asm volatile("s_waitcnt vmcnt(3)" ::: "memory");
  __builtin_amdgcn_s_barrier();

#pragma unroll 1
  for (int kt = 0; kt < NKT; kt++) {
    int buf = kt & 1, nbuf = buf ^ 1;
    int ktn = (kt + 1 < NKT) ? kt + 1 : kt;  // tail: restage (keeps vmcnt counts)
    s16x8 bf0, bf1, bf2, bf3, af0, af1;
    // ===== phase 0: ks=0, mf 0-1 =====
    bf0 = rdB(buf, 0, 0); bf1 = rdB(buf, 0, 1);
    bf2 = rdB(buf, 0, 2); bf3 = rdB(buf, 0, 3);
    af0 = rdA(buf, 0, 0); af1 = rdA(buf, 0, 1);
    stageB(nbuf, ktn, 0);
    __builtin_amdgcn_s_barrier();
    asm volatile("s_waitcnt lgkmcnt(0)" ::: "memory");
    __builtin_amdgcn_sched_barrier(0);
    __builtin_amdgcn_s_setprio(1);
    acc[0][0] = MFMA16(af0, bf0, acc[0][0], 0, 0, 0);
    acc[0][1] = MFMA16(af0, bf1, acc[0][1], 0, 0, 0);
    acc[0][2] = MFMA16(af0, bf2, acc[0][2], 0, 0, 0);
    acc[0][3] = MFMA16(af0, bf3, acc[0][3], 0, 0, 0);
    acc[1][0] = MFMA16(af1, bf0, acc[1][0], 0, 0, 0);
    acc[1][1] = MFMA16(af1, bf1, acc[1][1], 0, 0, 0);
    acc[1][2] = MFMA16(af1, bf2, acc[1][2], 0, 0, 0);
    acc[1][3] = MFMA16(af1, bf3, acc[1][3], 0, 0, 0);
    __builtin_amdgcn_s_setprio(0);
    __builtin_amdgcn_s_barrier();
    // ===== phase 1: ks=0, mf 2-3 =====
    af0 = rdA(buf, 0, 2); af1 = rdA(buf, 0, 3);
    stageA(nbuf, ktn, 0);
    __builtin_amdgcn_s_barrier();
    asm volatile("s_waitcnt lgkmcnt(0)" ::: "memory");
    __builtin_amdgcn_sched_barrier(0);
    __builtin_amdgcn_s_setprio(1);
    acc[2][0] = MFMA16(af0, bf0, acc[2][0], 0, 0, 0);
    acc[2][1] = MFMA16(af0, bf1, acc[2][1], 0, 0, 0);
    acc[2][2] = MFMA16(af0, bf2, acc[2][2], 0, 0, 0);
    acc[2][3] = MFMA16(af0, bf3, acc[2][3], 0, 0, 0);
    acc[3][0] = MFMA16(af1, bf0, acc[3][0], 0, 0, 0);
    acc[3][1] = MFMA16(af1, bf1, acc[3][1], 0, 0, 0);
    acc[3][2] = MFMA16(af1, bf2, acc[3][2], 0, 0, 0);
    acc[3][3] = MFMA16(af1, bf3, acc[3][3], 0, 0, 0);
    __builtin_amdgcn_s_setprio(0);
    asm volatile("s_waitcnt vmcnt(3)" ::: "memory");  // k-half1(kt) resident
    __builtin_amdgcn_s_barrier();
    // ===== phase 2: ks=1, mf 0-1 =====
    bf0 = rdB(buf, 1, 0); bf1 = rdB(buf, 1, 1);
    bf2 = rdB(buf, 1, 2); bf3 = rdB(buf, 1, 3);
    af0 = rdA(buf, 1, 0); af1 = rdA(buf, 1, 1);
    stageB(nbuf, ktn, 1);
    __builtin_amdgcn_s_barrier();
    asm volatile("s_waitcnt lgkmcnt(0)" ::: "memory");
    __builtin_amdgcn_sched_barrier(0);
    __builtin_amdgcn_s_setprio(1);
    acc[0][0] = MFMA16(af0, bf0, acc[0][0], 0, 0, 0);
    acc[0][1] = MFMA16(af0, bf1, acc[0][1], 0, 0, 0);
    acc[0][2] = MFMA16(af0, bf2, acc[0][2], 0, 0, 0);
    acc[0][3] = MFMA16(af0, bf3, acc[0][3], 0, 0, 0);
    acc[1][0] = MFMA16(af1, bf0, acc[1][0], 0, 0, 0);
    acc[1][1] = MFMA16(af1, bf1, acc[1][1], 0, 0, 0);
    acc[1][2] = MFMA16(af1, bf2, acc[1][2], 0, 0, 0);
    acc[1][3] = MFMA16(af1, bf3, acc[1][3], 0, 0, 0);
    __builtin_amdgcn_s_setprio(0);
    __builtin_amdgcn_s_barrier();
    // ===== phase 3: ks=1, mf 2-3 =====
    af0 = rdA(buf, 1, 2); af1 = rdA(buf, 1, 3);
    stageA(nbuf, ktn, 1);
    __builtin_amdgcn_s_barrier();
    asm volatile("s_waitcnt lgkmcnt(0)" ::: "memory");
    __builtin_amdgcn_sched_barrier(0);
    __builtin_amdgcn_s_setprio(1);
    acc[2][0] = MFMA16(af0, bf0, acc[2][0], 0, 0, 0);
    acc[2][1] = MFMA16(af0, bf1, acc[2][1], 0, 0, 0);
    acc[2][2] = MFMA16(af0, bf2, acc[2][2], 0, 0, 0);
    acc[2][3] = MFMA16(af0, bf3, acc[2][3], 0, 0, 0);
    acc[3][0] = MFMA16(af1, bf0, acc[3][0], 0, 0, 0);
    acc[3][1] = MFMA16(af1, bf1, acc[3][1], 0, 0, 0);
    acc[3][2] = MFMA16(af1, bf2, acc[3][2], 0, 0, 0);
    acc[3][3] = MFMA16(af1, bf3, acc[3][3], 0, 0, 0);
    __builtin_amdgcn_s_setprio(0);
    asm volatile("s_waitcnt vmcnt(3)" ::: "memory");  // k-half0(kt+1) resident
    __builtin_amdgcn_s_barrier();
  }

  // ---- epilogue ----
#pragma unroll
  for (int mf = 0; mf < 4; mf++) {
#pragma unroll
    for (int nf = 0; nf < 4; nf++) {
#pragma unroll
      for (int i = 0; i < 4; i++) {
        float v = acc[mf][nf][i];
        int mm = m0 + wm * 64 + mf * 16 + lg * 4 + i;
        int nn = n0 + wn * 64 + nf * 16 + l15;
        if (MODE == 0) {
          int wsel = nn >> 11, n2 = nn & 2047;
          int h = n2 >> 7, dh = n2 & (HD - 1);
          int b = mm >> 11, s2 = mm & (SQ - 1);
          Obf[(size_t)wsel * MR * HD * NH +
              ((size_t)(b * NH + h) * SQ + s2) * HD + dh] = f2bf(v);
        } else {
          Ofp[(size_t)mm * DIMD + nn] = v;
        }
      }
    }
  }
}

// ---------------- flash attention (swapped QK^T, in-lane softmax) ----------
__global__ __launch_bounds__(512, 4) void attn_kernel(
    const u16* __restrict__ Q, const u16* __restrict__ K,
    const u16* __restrict__ Vt, u16* __restrict__ Aout) {
  __shared__ alignas(16) u16 Ksh[2][KBLK * HD];   // 2 x 16 KB
  __shared__ alignas(16) u16 Vsh[2][HD * KBLK];   // 2 x 16 KB
  __shared__ alignas(16) u16 Pl[8][16 * KBLK];    // 16 KB (per-wave, swizzled)
  int t = threadIdx.x;
  int wid = t >> 6, l = t & 63, l15 = l & 15, lg = l >> 4;
  int orig = blockIdx.x;
  int bid = (orig & 7) * 64 + (orig >> 3);
  int qb = bid & 15, bh = bid >> 4;
  int q0 = qb * QBLK + wid * 16;
  const u16* Qb = Q + ((size_t)bh * SQ + q0) * HD;
  const u16* Kb = K + (size_t)bh * SQ * HD;
  const u16* Vb = Vt + (size_t)bh * HD * SQ;

  s16x8 qf[4];
#pragma unroll
  for (int ks = 0; ks < 4; ks++)
    qf[ks] = *(const s16x8*)(Qb + (size_t)l15 * HD + ks * 32 + lg * 8);

  int o0 = t * 16, o1 = t * 16 + 8192;
  int kr0 = o0 >> 8, kc0 = (o0 & 255) ^ ((kr0 & 7) << 4);
  int kr1 = o1 >> 8, kc1 = (o1 & 255) ^ ((kr1 & 7) << 4);
  int vr0 = o0 >> 7, vc0 = (o0 & 127) ^ ((vr0 & 7) << 4);
  int vr1 = o1 >> 7, vc1 = (o1 & 127) ^ ((vr1 & 7) << 4);

  auto stage = [&](int buf, int kb) {
    const u16* Kt = Kb + (size_t)kb * KBLK * HD;
    const u16* Vs = Vb + kb * KBLK;
    gld16(Kt + (size_t)kr0 * HD + (kc0 >> 1), &Ksh[buf][o0 >> 1]);
    gld16(Kt + (size_t)kr1 * HD + (kc1 >> 1), &Ksh[buf][o1 >> 1]);
    gld16(Vs + (size_t)vr0 * SQ + (vc0 >> 1), &Vsh[buf][o0 >> 1]);
    gld16(Vs + (size_t)vr1 * SQ + (vc1 >> 1), &Vsh[buf][o1 >> 1]);
  };

  f32x4 acc[8];
#pragma unroll
  for (int i = 0; i < 8; i++) acc[i] = (f32x4){0.f, 0.f, 0.f, 0.f};
  float m = -3.0e38f, lsum = 0.f;

  stage(0, 0);
  __syncthreads();

#pragma unroll 1
  for (int kb = 0; kb < SQ / KBLK; kb++) {
    int cur = kb & 1;
    if (kb + 1 < SQ / KBLK) stage(cur ^ 1, kb + 1);
    f32x4 sa[4];
#pragma unroll
    for (int cb = 0; cb < 4; cb++) sa[cb] = (f32x4){0.f, 0.f, 0.f, 0.f};
    __builtin_amdgcn_s_setprio(1);
#pragma unroll
    for (int ks = 0; ks < 4; ks++) {
#pragma unroll
      for (int cb = 0; cb < 4; cb++) {
        int r = cb * 16 + l15;
        int off = r * 256 + ((ks * 64 + lg * 16) ^ ((r & 7) << 4));
        s16x8 kf = *(const s16x8*)((const char*)&Ksh[cur][0] + off);
        sa[cb] = MFMA16(kf, qf[ks], sa[cb], 0, 0, 0);
      }
    }
    __builtin_amdgcn_s_setprio(0);
    float rm = sa[0][0];
#pragma unroll
    for (int cb = 0; cb < 4; cb++)
#pragma unroll
      for (int i = 0; i < 4; i++) rm = fmaxf(rm, sa[cb][i]);
    rm = fmaxf(rm, __shfl_xor(rm, 16));
    rm = fmaxf(rm, __shfl_xor(rm, 32));
    if (!__all(rm <= m + 8.0f)) {
      float mn = fmaxf(m, rm);
      float al = __expf(m - mn);
      m = mn;
      float alq[4];
#pragma unroll
      for (int i = 0; i < 4; i++) alq[i] = __shfl(al, lg * 4 + i, 16);
#pragma unroll
      for (int c2 = 0; c2 < 8; c2++)
#pragma unroll
        for (int i = 0; i < 4; i++) acc[c2][i] *= alq[i];
      lsum *= al;
    }
    float ps = 0.f;
#pragma unroll
    for (int cb = 0; cb < 4; cb++)
#pragma unroll
      for (int i = 0; i < 4; i++) {
        sa[cb][i] = __expf(sa[cb][i] - m);
        ps += sa[cb][i];
      }
    ps += __shfl_xor(ps, 16);
    ps += __shfl_xor(ps, 32);
    lsum += ps;
#pragma unroll
    for (int cb = 0; cb < 4; cb++) {
      u32 lo = (u32)f2bf(sa[cb][0]) | ((u32)f2bf(sa[cb][1]) << 16);
      u32 hi = (u32)f2bf(sa[cb][2]) | ((u32)f2bf(sa[cb][3]) << 16);
      int off = l15 * 128 + ((cb * 32 + lg * 8) ^ ((l15 & 7) << 4));
      *(uint2*)((char*)&Pl[wid][0] + off) = make_uint2(lo, hi);
    }
    asm volatile("s_waitcnt lgkmcnt(0)" ::: "memory");
    __builtin_amdgcn_sched_barrier(0);
    s16x8 pf[2];
#pragma unroll
    for (int k2 = 0; k2 < 2; k2++) {
      int off = l15 * 128 + ((k2 * 64 + lg * 16) ^ ((l15 & 7) << 4));
      pf[k2] = *(const s16x8*)((const char*)&Pl[wid][0] + off);
    }
    __builtin_amdgcn_s_setprio(1);
#pragma unroll
    for (int c2 = 0; c2 < 8; c2++) {
#pragma unroll
      for (int k2 = 0; k2 < 2; k2++) {
        int r = c2 * 16 + l15;
        int off = r * 128 + ((k2 * 64 + lg * 16) ^ ((r & 7) << 4));
        s16x8 vf = *(const s16x8*)((const char*)&Vsh[cur][0] + off);
        acc[c2] = MFMA16(pf[k2], vf, acc[c2], 0, 0, 0);
      }
    }
    __builtin_amdgcn_s_setprio(0);
    __syncthreads();
  }
  float rin = 1.0f / lsum;
  float rq[4];
#pragma unroll
  for (int i = 0; i < 4; i++) rq[i] = __shfl(rin, lg * 4 + i, 16);
  int b = bh >> 4, h = bh & (NH - 1);
#pragma unroll
  for (int c2 = 0; c2 < 8; c2++) {
#pragma unroll
    for (int i = 0; i < 4; i++) {
      int q = q0 + lg * 4 + i;
      int dh = c2 * 16 + l15;
      Aout[((size_t)b * SQ + q) * DIMD + h * HD + dh] = f2bf(acc[c2][i] * rq[i]);
    }
  }
}

extern "C" void kernel_launch(void* const* d_in, const int* in_sizes, int n_in,
                              void* d_out, int out_size, void* d_ws, size_t ws_size,
                              hipStream_t stream) {
  (void)in_sizes; (void)n_in; (void)out_size; (void)ws_size;
  const float* x    = (const float*)d_in[0];
  const float* wq   = (const float*)d_in[1];
  const float* wk   = (const float*)d_in[2];
  const float* wv   = (const float*)d_in[3];
  const float* wo   = (const float*)d_in[4];
  const float* cosT = (const float*)d_in[5];
  const float* sinT = (const float*)d_in[6];
  float* out = (float*)d_out;

  char* p = (char*)d_ws;
  const size_t SZ_MD = (size_t)MR * DIMD * 2;    // 16.78 MB
  const size_t SZ_W  = (size_t)DIMD * DIMD * 2;  // 8.39 MB
  u16* xb   = (u16*)p; p += SZ_MD;
  u16* wqb  = (u16*)p; p += SZ_W;   // wq,wk,wv contiguous => one N=6144 GEMM
  u16* wkb  = (u16*)p; p += SZ_W;
  u16* wvb  = (u16*)p; p += SZ_W;
  u16* wob  = (u16*)p; p += SZ_W;
  u16* Qraw = (u16*)p; p += SZ_MD;  // Qraw,Kraw,Vraw contiguous (wsel scatter)
  u16* Kraw = (u16*)p; p += SZ_MD;
  u16* Vraw = (u16*)p; p += SZ_MD;
  u16* Qr   = (u16*)p; p += SZ_MD;
  u16* Kr   = (u16*)p; p += SZ_MD;
  u16* Vt   = (u16*)p; p += SZ_MD;
  u16* attnout = Qraw;  // Qraw dead after rope; reuse

  cvt_bf16<<<1024, 256, 0, stream>>>(x,  xb,  MR * DIMD / 4);
  cvt_bf16<<<512,  256, 0, stream>>>(wq, wqb, DIMD * DIMD / 4);
  cvt_bf16<<<512,  256, 0, stream>>>(wk, wkb, DIMD * DIMD / 4);
  cvt_bf16<<<512,  256, 0, stream>>>(wv, wvb, DIMD * DIMD / 4);
  cvt_bf16<<<512,  256, 0, stream>>>(wo, wob, DIMD * DIMD / 4);

  gemm8p<0><<<768, 512, 0, stream>>>(xb, wqb, Qraw, nullptr);
  rope_kernel<<<dim3(16384, 2), 256, 0, stream>>>(Qraw, Kraw, Qr, Kr, cosT, sinT);
  transpose_v<<<dim3(32, 2, 32), 256, 0, stream>>>(Vraw, Vt);
  attn_kernel<<<512, 512, 0, stream>>>(Qr, Kr, Vt, attnout);
  gemm8p<1><<<256, 512, 0, stream>>>(attnout, wob, nullptr, out);
}